// Round 8
// baseline (294.709 us; speedup 1.0000x reference)
//
#include <hip/hip_runtime.h>

// ARIMA(2,1,2) residual recurrence — DRAM-page-friendly decomposition.
//
// eps_j = (y[j+3]-y[j+2]-mu-phi0*y[j+2]-phi1*y[j+1]) - q0*eps_{j-1} - q1*eps_{j-2}
// out[b,0..4092] = eps, out[b,4093..4094] = 0.
//
// R8 theory: all prior rounds (R1-R7) pinned at 3.5-3.9 TB/s delivered BW
// regardless of occupancy/fences/double-buffering. Common factor: 64-col
// tiles => 256B per DRAM-page visit at 16KB stride. This kernel makes every
// page visit ~1.3KB:
//   - 1 wave = 16 rows x one whole 256-output chunk
//   - stage: per row, SIX consecutive 256B scalar loads (row-contiguous run)
//   - compute: 4 lanes per row = 4 sub-chunks of 64 outputs, warm-up 61
//     (warm data comes from the staged tile -> no extra HBM traffic)
//   - eps to separate LDS buffer (no in-place WAR races), dump: per row,
//     FOUR consecutive 256B stores (1KB run)
// Col-major LDS [col][17]: staging/dump use 17*lane addressing (bijective
// mod 32 banks => conflict-free); compute reads are 4-way (accepted).
// LDS 39.7KB -> 4 blocks/CU: low occupancy BY DESIGN (R4 proved occupancy
// is not the lever; this isolates the burst-granularity variable).

#define TSEQ   4096
#define TOUT   4095
#define NJ     4093
#define CHUNK  256
#define NCHUNK 16
#define ROWS   16
#define RP     17      // LDS row pitch (16 rows + 1 pad)
#define TC     328     // y-tile cols allocated (max used: 326)

__global__ __launch_bounds__(64) void arima_eps_pg(
    const float* __restrict__ y,
    const float* __restrict__ phi,
    const float* __restrict__ theta,
    const float* __restrict__ mu,
    float* __restrict__ out)
{
    __shared__ float ylds[TC][RP];      // y tile: [tile col][row]
    __shared__ float elds[CHUNK][RP];   // eps:    [out col][row]

    const int lane = threadIdx.x;
    const int g = blockIdx.x >> 4;      // 16-row group
    const int c = blockIdx.x & (NCHUNK - 1);
    const int rowbase = g * ROWS;

    const float p0 = phi[0], p1v = phi[1];
    const float q0 = theta[0], q1 = theta[1];
    const float m  = mu[0];
    const float c1 = 1.0f + p0;         // tg = y[j+3]-c1*y[j+2]-p1*y[j+1]-m

    const float* __restrict__ Y = y + (size_t)rowbase * TSEQ;
    float* __restrict__ O       = out + (size_t)rowbase * TOUT;

    const int j0 = c * CHUNK;
    const int j1 = min(j0 + CHUNK, NJ);
    const int tbase = max(j0 - 64, 0);          // tile start y-col (64-aligned)
    const int nc = min(TSEQ - tbase, 324);      // staged cols (320 or 324)

    // ---- stage: per row, 6 consecutive 256B coalesced loads ----
    for (int i = 0; i < ROWS; ++i) {
        const float* rp = Y + (size_t)i * TSEQ + tbase;
        #pragma unroll
        for (int b = 0; b < 6; ++b) {
            const int idx = b * 64 + lane;
            if (idx < nc) ylds[idx][i] = rp[idx];
        }
    }
    asm volatile("s_waitcnt lgkmcnt(0)" ::: "memory");

    // ---- recurrence: lane -> (row r, sub-chunk s of 64 outputs) ----
    const int r = lane & 15;
    const int s = lane >> 4;
    const int jout0 = j0 + s * 64;              // outputs [jout0, jout0+64)
    const int jstart = max(jout0 - 61, 0);      // 61-step warm-up (c==0,s==0: 0)
    const int coff = jstart + 3 - tbase;        // tile col of y[j+3] at t=0

    float yp2 = ylds[jstart + 1 - tbase][r];    // y[jstart+1]
    float yp1 = ylds[jstart + 2 - tbase][r];    // y[jstart+2]
    float e1 = 0.f, e2 = 0.f;

    // uniform 128 steps for ALL lanes (warm<=61 + 64 out + junk tail; stores
    // predicated). Junk steps read staged-or-uninit LDS (cols < 328, in
    // bounds) and only corrupt state after the last real store.
    for (int t = 0; t < 128; t += 8) {
        float yv[8];
        #pragma unroll
        for (int k = 0; k < 8; ++k) yv[k] = ylds[coff + t + k][r];
        #pragma unroll
        for (int k = 0; k < 8; ++k) {
            const float y3 = yv[k];
            float tg = __builtin_fmaf(-c1, yp1, y3);
            tg = __builtin_fmaf(-p1v, yp2, tg) - m;
            const float e = __builtin_fmaf(-q1, e2,
                              __builtin_fmaf(-q0, e1, tg));
            const int j = jstart + t + k;
            const int u = j - jout0;
            if (u >= 0 && u < 64) elds[s * 64 + u][r] = e;
            e2 = e1; e1 = e; yp2 = yp1; yp1 = y3;
        }
    }
    asm volatile("s_waitcnt lgkmcnt(0)" ::: "memory");

    // ---- dump: per row, 4 consecutive 256B coalesced stores (1KB run) ----
    const int cnt = j1 - j0;                    // 256 (or 253 for c==15)
    for (int i = 0; i < ROWS; ++i) {
        float* orow = O + (size_t)i * TOUT + j0;
        #pragma unroll
        for (int q = 0; q < 4; ++q) {
            const int u = q * 64 + lane;
            if (u < cnt) orow[u] = elds[u][i];
        }
    }

    // trailing Q zeros (harness poisons d_out)
    if (c == NCHUNK - 1 && lane < ROWS * 2) {
        const int i = lane >> 1;
        O[(size_t)i * TOUT + NJ + (lane & 1)] = 0.f;
    }
}

extern "C" void kernel_launch(void* const* d_in, const int* in_sizes, int n_in,
                              void* d_out, int out_size, void* d_ws, size_t ws_size,
                              hipStream_t stream) {
    const float* y     = (const float*)d_in[0];
    const float* phi   = (const float*)d_in[1];
    const float* theta = (const float*)d_in[2];
    const float* mu    = (const float*)d_in[3];
    float* out         = (float*)d_out;

    int B = in_sizes[0] / TSEQ;                 // 8192
    int rowgroups = B / ROWS;                   // 512
    dim3 block(64);
    dim3 grid(rowgroups * NCHUNK);              // 8192 single-wave blocks
    arima_eps_pg<<<grid, block, 0, stream>>>(y, phi, theta, mu, out);
}

// Round 9
// 93.445 us; speedup vs baseline: 3.1538x; 3.1538x over previous
//
#include <hip/hip_runtime.h>

// ARIMA(2,1,2) residual recurrence — R2 champion structure + NT output stores.
//
// eps_j = (y[j+3]-y[j+2]-mu-phi0*y[j+2]-phi1*y[j+1]) - th0*eps_{j-1} - th1*eps_{j-2}
// out[b, 0..4092] = eps, out[b, 4093..4094] = 0.
//
// R9 theory: R2/R5/R6/R7 all pinned at 3.85-3.95 TB/s delivered. Working set
// y(128MB)+out(134MB) = 262MB > 256MB L3: the write stream evicts y every
// pass (profiled FETCH stays ~100MB on late dispatches -> no L3 retention).
// Non-temporal stores keep the write stream out of L3 -> y stays resident ->
// steady-state reads become L3 hits, HBM carries only the 134MB write stream.
// ONE variable changed vs the 64.3us R2 champion: NT stores.

#define TSEQ  4096
#define TOUT  4095
#define NJ    4093
#define CHUNK 256
#define WARM  64
#define TILE  64
#define PITCH 65

__global__ __launch_bounds__(64) void arima_eps_nt(
    const float* __restrict__ y,
    const float* __restrict__ phi,
    const float* __restrict__ theta,
    const float* __restrict__ mu,
    float* __restrict__ out, int B)
{
    __shared__ float lds[TILE][PITCH];   // [local col][row(=lane)]

    const int lane = threadIdx.x;
    const int g = blockIdx.x >> 4;       // row group (64 rows each)
    const int c = blockIdx.x & 15;       // chunk within row
    const int rowbase = g * 64;
    (void)B;

    const float p0 = phi[0], p1 = phi[1];
    const float q0 = theta[0], q1 = theta[1];
    const float m  = mu[0];

    const float* __restrict__ Y = y + (size_t)rowbase * TSEQ;
    float* __restrict__ O       = out + (size_t)rowbase * TOUT;

    const int j0 = c * CHUNK;
    const int j1 = min(j0 + CHUNK, NJ);
    const int jw = max(j0 - WARM, 0);

    const int lrow = lane >> 4;          // row offset within quad
    const int lcol = (lane & 15) * 4;    // col base within tile

    // global (coalesced float4) -> LDS transposed
    auto load_tile = [&](int tb) {
        #pragma unroll
        for (int qq = 0; qq < 16; ++qq) {
            const int r = qq * 4 + lrow;
            const float4 v = *reinterpret_cast<const float4*>(
                &Y[(size_t)r * TSEQ + tb + lcol]);
            lds[lcol + 0][r] = v.x;
            lds[lcol + 1][r] = v.y;
            lds[lcol + 2][r] = v.z;
            lds[lcol + 3][r] = v.w;
        }
    };

    float a, b, e1 = 0.f, e2 = 0.f;

    // 8 batched LDS reads -> 8 recurrence steps -> 8 in-place eps writes
    auto step8 = [&](int cb) {
        float yv[8], ev[8];
        #pragma unroll
        for (int k = 0; k < 8; ++k) yv[k] = lds[cb + k][lane];
        #pragma unroll
        for (int k = 0; k < 8; ++k) {
            const float cc  = yv[k];
            const float tgt = cc - b - m - p0 * b - p1 * a;
            const float e   = tgt - q0 * e1 - q1 * e2;
            ev[k] = e;
            e2 = e1; e1 = e; a = b; b = cc;
        }
        #pragma unroll
        for (int k = 0; k < 8; ++k) lds[cb + k][lane] = ev[k];
    };

    // coalesced dump of eps cols [max(jt,j0), min(jcur,j1)) — NT stores
    auto dump = [&](int jt, int jcur, int tb) {
        const int jd  = max(jt, j0);
        const int je  = min(jcur, j1);
        const int cnt = je - jd;
        if (cnt > 0) {
            const int dcol = jd + 3 - tb;
            float* op = O + jd + lane;
            const bool on = lane < cnt;
            #pragma unroll 8
            for (int r = 0; r < 64; ++r) {
                if (on) __builtin_nontemporal_store(lds[dcol + lane][r],
                                                    &op[(size_t)r * TOUT]);
            }
        }
    };

    // ---- tile 0: cols jw..jw+63; init a,b from cols jw+1, jw+2 ----
    int tb = jw;
    load_tile(tb);
    __syncthreads();
    {
        float yv[8], ev[5];
        #pragma unroll
        for (int k = 0; k < 8; ++k) yv[k] = lds[k][lane];
        a = yv[1]; b = yv[2];            // e1 = e2 = 0 (zero initial state)
        #pragma unroll
        for (int k = 3; k < 8; ++k) {
            const float cc  = yv[k];
            const float tgt = cc - b - m - p0 * b - p1 * a;
            const float e   = tgt - q0 * e1 - q1 * e2;
            ev[k - 3] = e;
            e2 = e1; e1 = e; a = b; b = cc;
        }
        #pragma unroll
        for (int k = 3; k < 8; ++k) lds[k][lane] = ev[k - 3];
    }
    #pragma unroll
    for (int cb = 8; cb < 64; cb += 8) step8(cb);
    int j = jw + 61;                      // outputs jw..jw+60 computed
    __syncthreads();
    dump(jw, j, tb);

    // ---- subsequent tiles: exactly 64 outputs each ----
    while (j < j1) {
        __syncthreads();                  // dump reads done before overwrite
        tb += TILE;
        load_tile(tb);
        __syncthreads();
        const int jt = j;                 // == tb - 3
        #pragma unroll
        for (int cb = 0; cb < 64; cb += 8) step8(cb);
        j = jt + 64;
        __syncthreads();
        dump(jt, j, tb);
    }

    // trailing Q zeros (harness poisons d_out) — NT stores
    if (c == 15) {
        __builtin_nontemporal_store(0.f, &O[(size_t)lane * TOUT + NJ]);
        __builtin_nontemporal_store(0.f, &O[(size_t)lane * TOUT + NJ + 1]);
    }
}

extern "C" void kernel_launch(void* const* d_in, const int* in_sizes, int n_in,
                              void* d_out, int out_size, void* d_ws, size_t ws_size,
                              hipStream_t stream) {
    const float* y     = (const float*)d_in[0];
    const float* phi   = (const float*)d_in[1];
    const float* theta = (const float*)d_in[2];
    const float* mu    = (const float*)d_in[3];
    float* out         = (float*)d_out;

    int B = in_sizes[0] / TSEQ;                 // 8192
    int rowgroups = B / 64;                     // 128
    dim3 block(64);
    dim3 grid(rowgroups * 16);                  // 2048 single-wave blocks
    arima_eps_nt<<<grid, block, 0, stream>>>(y, phi, theta, mu, out, B);
}